// Round 3
// baseline (98.859 us; speedup 1.0000x reference)
//
#include <hip/hip_runtime.h>

#define HW 16384

typedef short bf16x8 __attribute__((ext_vector_type(8)));
typedef float f32x4 __attribute__((ext_vector_type(4)));

// output offsets (floats): cls_score, cls_score_neg, distances, distances_neg, probs_ori
static constexpr size_t OFF0 = 0;
static constexpr size_t OFF1 = 10616832;   // 8*81*16384
static constexpr size_t OFF2 = 21233664;
static constexpr size_t OFF3 = 31850496;
static constexpr size_t OFF4 = 63700992;   // OFF3 + 3*10616832

static __device__ __forceinline__ unsigned short f2bf(float f) {
  unsigned int u = __float_as_uint(f);
  u += 0x7fffu + ((u >> 16) & 1u);   // RNE
  return (unsigned short)(u >> 16);
}

// write one (row R, channel j) bf16 value into the MFMA A-frag layout
static __device__ __forceinline__ void frag_write(unsigned short* wsA, int R, int j,
                                                  unsigned short v) {
  const int mt = R >> 4;
  const int ks = j >> 5;
  const int hi = (j >> 3) & 3;
  const int jj = j & 7;
  const int lane = hi * 16 + (R & 15);
  wsA[((size_t)((mt * 4 + ks) * 64 + lane)) * 8 + jj] = v;
}

// ---------------- fused prep: reps + full 3-stage chain + norm + frag pack ----------------
__global__ __launch_bounds__(128) void prep_all(const float* __restrict__ rw,
                                                const float* __restrict__ rb,
                                                const float* __restrict__ nw,
                                                const float* __restrict__ nb,
                                                unsigned short* __restrict__ wsA) {
  const int b = blockIdx.x;
  const int k = b / 81, o = b % 81;
  const int j = threadIdx.x;
  __shared__ __align__(16) float hrow[128];
  __shared__ float red[2];

  float v = rw[o * 128 + j] + rb[o * 128 + j];
  float sq = v * v;
#pragma unroll
  for (int m = 1; m < 64; m <<= 1) sq += __shfl_xor(sq, m, 64);
  if ((j & 63) == 0) red[j >> 6] = sq;
  __syncthreads();
  const float r = v / fmaxf(sqrtf(red[0] + red[1]), 1e-12f);
  __syncthreads();
  hrow[j] = r;
  __syncthreads();

  float acc = 0.f;
#pragma unroll
  for (int l = 0; l < 3; ++l) {
    const float4* Wr = (const float4*)(nw + (((size_t)(k * 3 + l)) * 128 + j) * 128);
    const float4* H  = (const float4*)hrow;
    float4 a = {0.f, 0.f, 0.f, 0.f};
#pragma unroll
    for (int q = 0; q < 32; ++q) {
      float4 wv = Wr[q]; float4 hv = H[q];
      a.x = fmaf(wv.x, hv.x, a.x); a.y = fmaf(wv.y, hv.y, a.y);
      a.z = fmaf(wv.z, hv.z, a.z); a.w = fmaf(wv.w, hv.w, a.w);
    }
    acc = (a.x + a.y) + (a.z + a.w) + nb[(k * 3 + l) * 128 + j];
    if (l < 2) acc = fmaxf(acc, 0.f);
    __syncthreads();
    if (l < 2) hrow[j] = acc;
    __syncthreads();
  }

  float sq2 = acc * acc;
#pragma unroll
  for (int m = 1; m < 64; m <<= 1) sq2 += __shfl_xor(sq2, m, 64);
  if ((j & 63) == 0) red[j >> 6] = sq2;
  __syncthreads();
  const float accn = acc / fmaxf(sqrtf(red[0] + red[1]), 1e-12f);

  frag_write(wsA, o * 4 + k + 1, j, f2bf(accn));
  if (k == 0) frag_write(wsA, o * 4, j, f2bf(r));
  if (b == 0) {
#pragma unroll
    for (int R = 324; R < 336; ++R) frag_write(wsA, R, j, (unsigned short)0);
  }
}

// ---------------- main fused kernel ----------------
__global__ __launch_bounds__(256) void main_kernel(const float* __restrict__ x,
                                                   const bf16x8* __restrict__ wsA,
                                                   float* __restrict__ out) {
  __shared__ __align__(16) char eLds[32768];   // E tile, then per-wave store staging
  __shared__ float ss[8][128];
  __shared__ float invn[128];

  const int b = blockIdx.x;
  const int n = b >> 7;
  const int p0 = (b & 127) << 7;
  const int t = threadIdx.x;
  const float* xb = x + ((size_t)n * 128) * HW + p0;

  // ---- build E tile: pack 4 channels/px -> ds_write_b64, swizzle on (px>>2)&7 ----
  {
    const int pq = (t & 31) * 4;
    const int cg = t >> 5;
    const int swz = (t & 7) << 4;
    float a0 = 0.f, a1 = 0.f, a2 = 0.f, a3 = 0.f;
#pragma unroll
    for (int i = 0; i < 4; ++i) {
      const int c0 = i * 32 + cg * 4;
      float4 v0 = *(const float4*)(xb + (size_t)(c0 + 0) * HW + pq);
      float4 v1 = *(const float4*)(xb + (size_t)(c0 + 1) * HW + pq);
      float4 v2 = *(const float4*)(xb + (size_t)(c0 + 2) * HW + pq);
      float4 v3 = *(const float4*)(xb + (size_t)(c0 + 3) * HW + pq);
      a0 = fmaf(v0.x, v0.x, fmaf(v1.x, v1.x, fmaf(v2.x, v2.x, fmaf(v3.x, v3.x, a0))));
      a1 = fmaf(v0.y, v0.y, fmaf(v1.y, v1.y, fmaf(v2.y, v2.y, fmaf(v3.y, v3.y, a1))));
      a2 = fmaf(v0.z, v0.z, fmaf(v1.z, v1.z, fmaf(v2.z, v2.z, fmaf(v3.z, v3.z, a2))));
      a3 = fmaf(v0.w, v0.w, fmaf(v1.w, v1.w, fmaf(v2.w, v2.w, fmaf(v3.w, v3.w, a3))));
      uint2 w;
      w.x = (unsigned)f2bf(v0.x) | ((unsigned)f2bf(v1.x) << 16);
      w.y = (unsigned)f2bf(v2.x) | ((unsigned)f2bf(v3.x) << 16);
      *(uint2*)(eLds + (((pq + 0) * 256 + c0 * 2) ^ swz)) = w;
      w.x = (unsigned)f2bf(v0.y) | ((unsigned)f2bf(v1.y) << 16);
      w.y = (unsigned)f2bf(v2.y) | ((unsigned)f2bf(v3.y) << 16);
      *(uint2*)(eLds + (((pq + 1) * 256 + c0 * 2) ^ swz)) = w;
      w.x = (unsigned)f2bf(v0.z) | ((unsigned)f2bf(v1.z) << 16);
      w.y = (unsigned)f2bf(v2.z) | ((unsigned)f2bf(v3.z) << 16);
      *(uint2*)(eLds + (((pq + 2) * 256 + c0 * 2) ^ swz)) = w;
      w.x = (unsigned)f2bf(v0.w) | ((unsigned)f2bf(v1.w) << 16);
      w.y = (unsigned)f2bf(v2.w) | ((unsigned)f2bf(v3.w) << 16);
      *(uint2*)(eLds + (((pq + 3) * 256 + c0 * 2) ^ swz)) = w;
    }
    float4 st = {a0, a1, a2, a3};
    *(float4*)&ss[cg][pq] = st;
  }
  __syncthreads();
  if (t < 128) {
    float s = 0.f;
#pragma unroll
    for (int g = 0; g < 8; ++g) s += ss[g][t];
    invn[t] = 1.f / fmaxf(sqrtf(s), 1e-12f);
  }
  __syncthreads();

  const int lane = t & 63;
  const int wv = t >> 6;        // wave 0..3, owns pixels [wv*32, wv*32+32)
  const int og = lane >> 4;
  const int px16 = lane & 15;

  // ---- B-fragments (registers); reads only this wave's 8KB slice of eLds ----
  bf16x8 bfrag[2][4];
  float ivp[2];
#pragma unroll
  for (int u = 0; u < 2; ++u) {
    const int p = (wv * 2 + u) * 16 + px16;
    const int swzr = ((p >> 2) & 7) << 4;
#pragma unroll
    for (int ks = 0; ks < 4; ++ks) {
      const int addr = (p * 256 + ks * 64 + (lane >> 4) * 16) ^ swzr;
      bfrag[u][ks] = *(const bf16x8*)(eLds + addr);
    }
    ivp[u] = invn[p];
  }

  // after this point eLds rows [wv*32, wv*32+32) == bytes [wv*8192, +8192) are
  // wave-private scratch: reuse as store-staging (no barrier needed).
  float* stg = (float*)(eLds + wv * 8192);

  float probs_arr[42];

#pragma unroll
  for (int mt = 0; mt < 21; ++mt) {
    bf16x8 afr[4];
#pragma unroll
    for (int ks = 0; ks < 4; ++ks) afr[ks] = wsA[(mt * 4 + ks) * 64 + lane];
    f32x4 c0 = {0.f, 0.f, 0.f, 0.f}, c1 = {0.f, 0.f, 0.f, 0.f};
#pragma unroll
    for (int ks = 0; ks < 4; ++ks) {
      c0 = __builtin_amdgcn_mfma_f32_16x16x32_bf16(afr[ks], bfrag[0][ks], c0, 0, 0, 0);
      c1 = __builtin_amdgcn_mfma_f32_16x16x32_bf16(afr[ks], bfrag[1][ks], c1, 0, 0, 0);
    }
    const int o = mt * 4 + og;
    const bool valid = (o < 81);
    // stage 6 outputs per (o,px): rows (u*24 + og*6 + j), padded stride 20
#pragma unroll
    for (int u = 0; u < 2; ++u) {
      const f32x4 c = u ? c1 : c0;
      const float iv = ivp[u];
      float q0 = fmaxf(2.f - 2.f * (c[0] * iv), 0.f);
      float q1 = fmaxf(2.f - 2.f * (c[1] * iv), 0.f);
      float q2 = fmaxf(2.f - 2.f * (c[2] * iv), 0.f);
      float q3 = fmaxf(2.f - 2.f * (c[3] * iv), 0.f);
      float d0 = sqrtf(q0), d1 = sqrtf(q1), d2 = sqrtf(q2), d3 = sqrtf(q3);
      float qmin = fminf(q1, fminf(q2, q3));
      float dmin = fminf(d1, fminf(d2, d3));
      float pneg = __expf(-2.f * qmin);
      float pori = __expf(-2.f * q0);
      float tt = d0 + 0.3f * fmaxf(2.f - dmin, 0.f);
      float pr = __expf(-2.f * tt * tt);
      probs_arr[mt * 2 + u] = valid ? pr : 0.f;
      float* su = stg + u * 480 + og * 120 + px16;
      su[0] = d0; su[20] = d1; su[40] = d2; su[60] = d3;
      su[80] = pneg; su[100] = pori;
    }
    // readback: 48 pairs (u,o_l,j) x 4 px-quads = 3 full-wave float4 stores
#pragma unroll
    for (int pass = 0; pass < 3; ++pass) {
      const int slot = pass * 64 + lane;
      const int pair = slot >> 2;          // 0..47
      const int quad = slot & 3;
      const int uu = pair >= 24;
      const int pr6 = pair - 24 * uu;      // 0..23
      const int ol = (pr6 * 43) >> 8;      // /6
      const int j = pr6 - 6 * ol;
      const int oo = mt * 4 + ol;
      f32x4 v = *(const f32x4*)(stg + pair * 20 + quad * 4);
      if (oo < 81) {
        const int px = p0 + wv * 32 + uu * 16 + quad * 4;
        const int idx81 = n * 81 + oo;
        size_t off;
        if (j == 0) off = OFF2 + (size_t)idx81 * HW;
        else if (j < 4) off = OFF3 + ((size_t)(idx81 * 3 + (j - 1))) * HW;
        else if (j == 4) off = OFF1 + (size_t)idx81 * HW;
        else off = OFF4 + (size_t)idx81 * HW;
        __builtin_nontemporal_store(v, (f32x4*)(out + off + px));
      }
    }
  }

  // ---- cls_score: normalize probs over o per pixel, staged float4 stores ----
  float isv[2];
#pragma unroll
  for (int u = 0; u < 2; ++u) {
    float s = 0.f;
#pragma unroll
    for (int mt = 0; mt < 21; ++mt) s += probs_arr[mt * 2 + u];
    s += __shfl_xor(s, 16, 64);
    s += __shfl_xor(s, 32, 64);
    isv[u] = 1.f / s;
  }
#pragma unroll
  for (int g = 0; g < 6; ++g) {
    const int nmt = (g < 5) ? 4 : 1;
#pragma unroll
    for (int mtl = 0; mtl < 4; ++mtl) {
      if (mtl < nmt) {
        const int mt = g * 4 + mtl;
#pragma unroll
        for (int u = 0; u < 2; ++u)
          stg[u * 320 + (mtl * 4 + og) * 20 + px16] = probs_arr[mt * 2 + u] * isv[u];
      }
    }
#pragma unroll
    for (int pass = 0; pass < 2; ++pass) {
      const int slot = pass * 64 + lane;
      const int pair = slot >> 2;          // 0..31
      const int quad = slot & 3;
      const int uu = pair >= 16;
      const int pp = pair - 16 * uu;       // 0..15
      const int mtl = pp >> 2;
      const int ol = pp & 3;
      const int oo = (g * 4 + mtl) * 4 + ol;
      f32x4 v = *(const f32x4*)(stg + pair * 20 + quad * 4);
      if (mtl < nmt && oo < 81) {
        const int px = p0 + wv * 32 + uu * 16 + quad * 4;
        const size_t off = OFF0 + (size_t)(n * 81 + oo) * HW;
        __builtin_nontemporal_store(v, (f32x4*)(out + off + px));
      }
    }
  }
}

extern "C" void kernel_launch(void* const* d_in, const int* in_sizes, int n_in,
                              void* d_out, int out_size, void* d_ws, size_t ws_size,
                              hipStream_t stream) {
  const float* x  = (const float*)d_in[0];
  const float* rw = (const float*)d_in[1];
  const float* rb = (const float*)d_in[2];
  const float* nw = (const float*)d_in[3];
  const float* nb = (const float*)d_in[4];
  float* out = (float*)d_out;
  unsigned short* wsA_us = (unsigned short*)d_ws;
  const bf16x8* wsA = (const bf16x8*)d_ws;

  hipLaunchKernelGGL(prep_all, dim3(243), dim3(128), 0, stream, rw, rb, nw, nb, wsA_us);
  hipLaunchKernelGGL(main_kernel, dim3(1024), dim3(256), 0, stream, x, wsA, out);
}